// Round 13
// baseline (296.648 us; speedup 1.0000x reference)
//
#include <hip/hip_runtime.h>
#include <hip/hip_fp16.h>

#define NN 100000
#define NE 1600000
#define IND 64
#define HID 128
#define NCLS 16
#define NGRP 3125         // 32-node groups per graph (3125*32 = 100000 exactly)
#define RBLK 125          // reduce1 blocks (per = NGRP/RBLK = 25)
#define NCRS 98           // coarse buckets per graph (1024 nodes each)
#define CAPC 18432        // coarse capacity (mean 16384, sigma 128 -> +16 sigma)
#define CAPF 656          // fine capacity per 32-node group (mean 512, +6.4 sigma)
#define NDCAP 48          // per-node LDS list capacity (mean 16; P(>48)~1e-9)
#define EPB1 8192         // edges per block in place_coarse
#define NBG1 ((NE + EPB1 - 1) / EPB1)   // 196 blocks per graph
#define FSPLIT 4          // blocks per coarse bucket in place_fine
#define FSPAN ((CAPC + FSPLIT - 1) / FSPLIT)   // 4608 edges max per part
#define PCB (2 * NBG1)    // merged kernel: coarse blocks (392)
#define CVB 782           // merged kernel: conv blocks (400000/512)
#define PKB 24            // merged kernel: packW blocks (12288/512)

// fp4 h1 tables (halve layer-2 gather bytes) iff HW MX converters exist.
#if __has_builtin(__builtin_amdgcn_cvt_scalef32_pk_f32_fp4) && \
    __has_builtin(__builtin_amdgcn_cvt_scalef32_pk_fp4_f32)
#define USE_FP4 1
#else
#define USE_FP4 0
#endif

typedef float v2f __attribute__((ext_vector_type(2)));
typedef __attribute__((ext_vector_type(8))) short short8v;   // 8 bf16 (4 VGPRs)
typedef __attribute__((ext_vector_type(4))) float f32x4;     // MFMA acc

// ---------------------------------------------------------------------------
// fp8 e4m3 helpers (HW cvt on gfx950; template HI so builtin sees a constant)
__device__ __forceinline__ float fp8_sw_unpack(unsigned b) {
    unsigned s = (b >> 7) & 1u, em = b & 0x7fu;
    return __uint_as_float((s << 31) | (em << 20)) * 0x1p+120f;
}
__device__ __forceinline__ unsigned fp8_sw_pack(float f) {
    float c = fminf(fmaxf(f, -448.f), 448.f) * 0x1p-120f;
    unsigned b = __float_as_uint(c);
    unsigned s = b >> 31; b &= 0x7fffffffu;
    b = b + 0x7ffffu + ((b >> 20) & 1u);
    unsigned em = b >> 20;
    if (em > 0x7eu) em = 0x7eu;
    return (s << 7) | em;
}
template<bool HI>
__device__ __forceinline__ unsigned pk8(float a, float b, unsigned old) {
#if __has_builtin(__builtin_amdgcn_cvt_pk_fp8_f32)
    return (unsigned)__builtin_amdgcn_cvt_pk_fp8_f32(a, b, (int)old, HI);
#else
    unsigned v = fp8_sw_pack(a) | (fp8_sw_pack(b) << 8);
    return HI ? ((old & 0x0000ffffu) | (v << 16)) : ((old & 0xffff0000u) | v);
#endif
}
template<bool HI>
__device__ __forceinline__ v2f upk8(unsigned u) {
#if __has_builtin(__builtin_amdgcn_cvt_pk_f32_fp8)
    return __builtin_amdgcn_cvt_pk_f32_fp8((int)u, HI);
#else
    unsigned x = HI ? (u >> 16) : u;
    v2f r; r.x = fp8_sw_unpack(x & 0xffu); r.y = fp8_sw_unpack((x >> 8) & 0xffu);
    return r;
#endif
}

// float -> bf16 bits (RNE) -- scalar fallback path
__device__ __forceinline__ short f2bf(float f) {
    unsigned u = __float_as_uint(f);
    return (short)((u + 0x7fffu + ((u >> 16) & 1u)) >> 16);
}

// HW packed f32x2 -> bf16x2 (RNE; gfx950 v_cvt_pk_bf16_f32, T12-verified)
__device__ __forceinline__ unsigned cvt2bf(float a, float b) {
    unsigned r;
    asm("v_cvt_pk_bf16_f32 %0, %1, %2" : "=v"(r) : "v"(a), "v"(b));
    return r;
}

// packed-fp32 accumulate: 8 cvt_pk + 8 v_pk_add_f32 per uint4 (16 fp8 vals)
__device__ __forceinline__ void bacc8v(v2f* a, uint4 v) {
    a[0] += upk8<false>(v.x); a[1] += upk8<true>(v.x);
    a[2] += upk8<false>(v.y); a[3] += upk8<true>(v.y);
    a[4] += upk8<false>(v.z); a[5] += upk8<true>(v.z);
    a[6] += upk8<false>(v.w); a[7] += upk8<true>(v.w);
}

#if USE_FP4
// fp4 accumulate: uint4 = 32 fp4 values -> a[16] v2f (16 cvt + 16 pk_add)
__device__ __forceinline__ void bacc4v(v2f* a, uint4 v) {
    v2f t;
    t = __builtin_amdgcn_cvt_scalef32_pk_f32_fp4(v.x, 1.0f, 0); a[0]  += t;
    t = __builtin_amdgcn_cvt_scalef32_pk_f32_fp4(v.x, 1.0f, 1); a[1]  += t;
    t = __builtin_amdgcn_cvt_scalef32_pk_f32_fp4(v.x, 1.0f, 2); a[2]  += t;
    t = __builtin_amdgcn_cvt_scalef32_pk_f32_fp4(v.x, 1.0f, 3); a[3]  += t;
    t = __builtin_amdgcn_cvt_scalef32_pk_f32_fp4(v.y, 1.0f, 0); a[4]  += t;
    t = __builtin_amdgcn_cvt_scalef32_pk_f32_fp4(v.y, 1.0f, 1); a[5]  += t;
    t = __builtin_amdgcn_cvt_scalef32_pk_f32_fp4(v.y, 1.0f, 2); a[6]  += t;
    t = __builtin_amdgcn_cvt_scalef32_pk_f32_fp4(v.y, 1.0f, 3); a[7]  += t;
    t = __builtin_amdgcn_cvt_scalef32_pk_f32_fp4(v.z, 1.0f, 0); a[8]  += t;
    t = __builtin_amdgcn_cvt_scalef32_pk_f32_fp4(v.z, 1.0f, 1); a[9]  += t;
    t = __builtin_amdgcn_cvt_scalef32_pk_f32_fp4(v.z, 1.0f, 2); a[10] += t;
    t = __builtin_amdgcn_cvt_scalef32_pk_f32_fp4(v.z, 1.0f, 3); a[11] += t;
    t = __builtin_amdgcn_cvt_scalef32_pk_f32_fp4(v.w, 1.0f, 0); a[12] += t;
    t = __builtin_amdgcn_cvt_scalef32_pk_f32_fp4(v.w, 1.0f, 1); a[13] += t;
    t = __builtin_amdgcn_cvt_scalef32_pk_f32_fp4(v.w, 1.0f, 2); a[14] += t;
    t = __builtin_amdgcn_cvt_scalef32_pk_f32_fp4(v.w, 1.0f, 3); a[15] += t;
}
// pack 2 relu-f32 into byte SEL of a fp4 word (clamp to e2m1 max 6)
template<int SEL>
__device__ __forceinline__ unsigned pk4(unsigned old, float a, float b) {
    return __builtin_amdgcn_cvt_scalef32_pk_fp4_f32(old, fminf(a, 6.0f),
                                                    fminf(b, 6.0f), 1.0f, SEL);
}
#endif

// 4 v2f (8 floats) * iv -> one bf16 granule (4 pk_mul + 4 cvt_pk = 8 VALU)
__device__ __forceinline__ short8v mk8(const v2f* a, float iv) {
    union { uint4 u; short8v s; } o;
    v2f t0 = a[0] * iv, t1 = a[1] * iv, t2 = a[2] * iv, t3 = a[3] * iv;
    o.u.x = cvt2bf(t0.x, t0.y);
    o.u.y = cvt2bf(t1.x, t1.y);
    o.u.z = cvt2bf(t2.x, t2.y);
    o.u.w = cvt2bf(t3.x, t3.y);
    return o.s;
}

// ---------------------------------------------------------------------------
// Merged prep + place_coarse (independent work; cursor zeroing precedes via
// memset). Blocks [0,392): coarse multisplit; [392,1174): feats->fp8;
// [1174,1198): weights->B-frags.
__global__ __launch_bounds__(512) void prep_coarse(
    const int* __restrict__ s0, const int* __restrict__ d0,
    const int* __restrict__ s1, const int* __restrict__ d1,
    int* __restrict__ gcurC,
    unsigned* __restrict__ pc0, unsigned* __restrict__ pc1,
    const float4* __restrict__ x, uint4* __restrict__ o8,
    const float* __restrict__ Ws1a, const float* __restrict__ Wn1a,
    const float* __restrict__ Ws1b, const float* __restrict__ Wn1b,
    const float* __restrict__ Ws2a, const float* __restrict__ Wn2a,
    const float* __restrict__ Ws2b, const float* __restrict__ Wn2b,
    short* __restrict__ wout) {
    __shared__ unsigned ebuf[EPB1];      // 32 KB, bucket-ordered edges
    __shared__ int h[128], off[128];     // hist / inclusive scan (98 used)
    __shared__ int hb[NCRS];             // reserved global base per bucket
    const int bi = blockIdx.x;
    const int tid = threadIdx.x;

    if (bi >= PCB) {
        if (bi < PCB + CVB) {
            // feats fp32 -> fp8 (16 elems / thread)
            int i = (bi - PCB) * 512 + tid;
            if (i >= NN * IND / 16) return;
            float4 v0 = x[4 * i + 0], v1 = x[4 * i + 1];
            float4 v2 = x[4 * i + 2], v3 = x[4 * i + 3];
            uint4 u;
            u.x = pk8<true>(v0.z, v0.w, pk8<false>(v0.x, v0.y, 0u));
            u.y = pk8<true>(v1.z, v1.w, pk8<false>(v1.x, v1.y, 0u));
            u.z = pk8<true>(v2.z, v2.w, pk8<false>(v2.x, v2.y, 0u));
            u.w = pk8<true>(v3.z, v3.w, pk8<false>(v3.x, v3.y, 0u));
            o8[i] = u;
        } else {
            // pack [Ws;Wn] stacks into bf16 MFMA B-fragments
            int t = (bi - PCB - CVB) * 512 + tid;
            if (t >= 12288) return;
            const float *Ws, *Wn; short* o; int KS;
            if (t < 2048)      { Ws = Ws1a; Wn = Wn1a; o = wout;         KS = 64;  }
            else if (t < 4096) { Ws = Ws1b; Wn = Wn1b; o = wout + 16384; KS = 64;  t -= 2048; }
            else if (t < 8192) { Ws = Ws2a; Wn = Wn2a; o = wout + 32768; KS = 128; t -= 4096; }
            else               { Ws = Ws2b; Wn = Wn2b; o = wout + 65536; KS = 128; t -= 8192; }
            int l = t & 63, f = t >> 6, nn = f & 7, kk = f >> 3;
            int col = nn * 16 + (l & 15);
            int k0 = kk * 32 + ((l >> 4) * 8);
            unsigned short v[8];
#pragma unroll
            for (int j = 0; j < 8; j++) {
                int k = k0 + j;
                float xx = (k < KS) ? Ws[k * 128 + col] : Wn[(k - KS) * 128 + col];
                v[j] = (unsigned short)f2bf(xx);
            }
            uint4 u;
            u.x = (unsigned)v[0] | ((unsigned)v[1] << 16);
            u.y = (unsigned)v[2] | ((unsigned)v[3] << 16);
            u.z = (unsigned)v[4] | ((unsigned)v[5] << 16);
            u.w = (unsigned)v[6] | ((unsigned)v[7] << 16);
            ((uint4*)o)[t] = u;
        }
        return;
    }

    // ---- coarse multisplit: entry = src | (dst&1023)<<17 ----
    const int g = bi >= NBG1;
    const int* src = g ? s1 : s0;
    const int* dst = g ? d1 : d0;
    unsigned* pc = g ? pc1 : pc0;
    const int base = (g ? bi - NBG1 : bi) * EPB1;
    int nle = NE - base; if (nle > EPB1) nle = EPB1;

    if (tid < 128) h[tid] = 0;
    __syncthreads();
    for (int j = tid; j < nle; j += 512) atomicAdd(&h[dst[base + j] >> 10], 1);
    __syncthreads();
    if (tid < 128) off[tid] = h[tid];
    __syncthreads();
    for (int o = 1; o < 128; o <<= 1) {
        int v = (tid < 128 && tid >= o) ? off[tid - o] : 0;
        __syncthreads();
        if (tid < 128) off[tid] += v;
        __syncthreads();
    }
    if (tid < NCRS) hb[tid] = h[tid] ? atomicAdd(&gcurC[g * NCRS + tid], h[tid]) : 0;
    __syncthreads();
    if (tid < 128) h[tid] = off[tid] - h[tid];   // h becomes scatter cursor (excl)
    __syncthreads();
    for (int j = tid; j < nle; j += 512) {
        int d = dst[base + j];
        int b = d >> 10;
        int pos = atomicAdd(&h[b], 1);
        ebuf[pos] = (unsigned)src[base + j] | ((unsigned)(d & 1023) << 17);
    }
    __syncthreads();
    const int wv = tid >> 6, lane = tid & 63;
    for (int b = wv; b < NCRS; b += 8) {
        int beg = b ? off[b - 1] : 0;
        int run = off[b] - beg;
        int gb = hb[b];
        if (gb + run > CAPC) run = CAPC - gb;
        for (int i = lane; i < run; i += 64)
            pc[(size_t)b * CAPC + gb + i] = ebuf[beg + i];
    }
}

// ---------------------------------------------------------------------------
// Level 2: FSPLIT blocks per coarse bucket; SINGLE-PASS LDS multisplit into
// 32 fine bins (32-node groups), global atomic cursor reservation, coalesced
// writeback. fine entry = src | (dst&31)<<17
__global__ __launch_bounds__(512) void place_fine(
    const unsigned* __restrict__ pc0, const unsigned* __restrict__ pc1,
    const int* __restrict__ gcurC,
    unsigned* __restrict__ pf0, unsigned* __restrict__ pf1,
    int* __restrict__ fcur) {      // [2][NCRS*32]
    __shared__ unsigned ibuf[FSPAN];     // 18.4 KB, raw slice
    __shared__ unsigned obuf[FSPAN];     // 18.4 KB, bin-ordered slice
    __shared__ int h2[32], off2[32], cur2[32], gb2[32];
    const int bi = blockIdx.x;
    const int g = bi >= NCRS * FSPLIT;
    const int idx = g ? bi - NCRS * FSPLIT : bi;
    const int c = idx >> 2, part = idx & (FSPLIT - 1);
    const unsigned* pc = g ? pc1 : pc0;
    unsigned* pf = g ? pf1 : pf0;
    int* fc = fcur + (size_t)g * NCRS * 32;
    int ecnt = gcurC[g * NCRS + c];
    if (ecnt > CAPC) ecnt = CAPC;
    int span = (ecnt + FSPLIT - 1) / FSPLIT;
    int st = part * span;
    int en = st + span; if (en > ecnt) en = ecnt;
    int n = en - st; if (n < 0) n = 0;
    const size_t cb = (size_t)c * CAPC + st;
    const int tid = threadIdx.x;
    const int wv = tid >> 6, lane = tid & 63;

    if (tid < 32) h2[tid] = 0;
    __syncthreads();
    for (int e = tid; e < n; e += 512) {
        unsigned u = pc[cb + e];
        ibuf[e] = u;
        atomicAdd(&h2[(u >> 22) & 31], 1);
    }
    __syncthreads();
    if (tid < 32) {
        gb2[tid] = h2[tid] ? atomicAdd(&fc[c * 32 + tid], h2[tid]) : 0;
        off2[tid] = h2[tid];
    }
    __syncthreads();
    for (int o = 1; o < 32; o <<= 1) {
        int v = (tid < 32 && tid >= o) ? off2[tid - o] : 0;
        __syncthreads();
        if (tid < 32) off2[tid] += v;
        __syncthreads();
    }
    if (tid < 32) cur2[tid] = off2[tid] - h2[tid];
    __syncthreads();
    for (int e = tid; e < n; e += 512) {
        unsigned u = ibuf[e];
        int sub = (u >> 22) & 31;
        int pos = atomicAdd(&cur2[sub], 1);
        obuf[pos] = (u & 0x1FFFFu) | (((u >> 17) & 31u) << 17);
    }
    __syncthreads();
    for (int sub = wv; sub < 32; sub += 8) {
        int beg = sub ? off2[sub - 1] : 0;
        int run = off2[sub] - beg;
        int gb = gb2[sub];
        if (gb >= CAPF) run = 0;
        else if (gb + run > CAPF) run = CAPF - gb;
        for (int i = lane; i < run; i += 64)
            pf[(size_t)(c * 32 + sub) * CAPF + gb + i] = obuf[beg + i];
    }
}

// ---------------------------------------------------------------------------
// Merged-graph fused SAGE layer: 512 threads, 32 nodes/block (16 thr/node),
// grid = 2*NGRP. The __syncthreads() after self-staging fences the binning
// writes (lcnt/ssrcL) that aggregation reads (R7 lesson).
// Layer-1 output h1 is fp4 (64B rows) when USE_FP4 -> layer-2 gather bytes
// halve. Layer-1 inputs (fb8/feats) stay fp8/fp32.
template<int KS, bool REDUCE>
__global__ __launch_bounds__(512) void sage_fused(
    const float* __restrict__ xin,
    const unsigned* __restrict__ x8a, const unsigned* __restrict__ x8b,
    const unsigned* __restrict__ pf0, const unsigned* __restrict__ pf1,
    const int* __restrict__ fcur,
    const short* __restrict__ Wfa, const short* __restrict__ Wfb,
    float* __restrict__ outRa, float* __restrict__ outRb,
    unsigned* __restrict__ outHa, unsigned* __restrict__ outHb) {
    constexpr int KT = (2 * KS) / 32;          // K-steps of 32
    __shared__ short8v sA[KT * 128];           // 2*KT KB (8 KB / 16 KB)
    __shared__ float otile[REDUCE ? 1 : 32 * 132];  // fp32 C transpose (layer1)
    __shared__ int lcnt[32];
    __shared__ int ssrcL[32 * NDCAP];          // per-node neighbor lists (6 KB)

    const int tid = threadIdx.x;
    const int g = blockIdx.x >= NGRP;
    const int gid = g ? blockIdx.x - NGRP : blockIdx.x;
    const int n0 = gid * 32;
    const unsigned* x8 = g ? x8b : x8a;
    const unsigned* pf = g ? pf1 : pf0;
    const int* fc = fcur + (size_t)g * NCRS * 32;
    const short8v* Wf = (const short8v*)(g ? Wfb : Wfa);
    const uint4* xb4 = (const uint4*)x8;

    if (tid < 32) lcnt[tid] = 0;
    __syncthreads();

    // ---- in-block binning: fine region -> per-node LDS lists ----
    {
        int ecnt = fc[gid];
        if (ecnt > CAPF) ecnt = CAPF;
        for (int e = tid; e < ecnt; e += 512) {
            unsigned u = pf[(size_t)gid * CAPF + e];
            int loc = (u >> 17) & 31;
            int pos = atomicAdd(&lcnt[loc], 1);
            if (pos < NDCAP) ssrcL[loc * NDCAP + pos] = (int)(u & 0x1FFFFu);
        }
    }

    // ---- self staging ----
    if constexpr (KS == IND) {
        if (tid < 256) {
            int node = tid >> 3, r = tid & 7;   // cols r*8..r*8+7
            float4 v0 = ((const float4*)xin)[(size_t)(n0 + node) * 16 + r * 2];
            float4 v1 = ((const float4*)xin)[(size_t)(n0 + node) * 16 + r * 2 + 1];
            union { uint4 u; short8v s; } o;
            o.u.x = cvt2bf(v0.x, v0.y);
            o.u.y = cvt2bf(v0.z, v0.w);
            o.u.z = cvt2bf(v1.x, v1.y);
            o.u.w = cvt2bf(v1.z, v1.w);
            int kk = r >> 2, kg = r & 3;
            sA[(kk * 128 + (node >> 4) * 64 + kg * 16 + (node & 15)) ^ (kk & 7)] = o.s;
        }
    } else {
#if USE_FP4
        if (tid < 128) {
            int node = tid >> 2, c4 = tid & 3;  // cols c4*32..+31 (fp4 uint4)
            uint4 u = xb4[(size_t)(n0 + node) * 4 + c4];
            v2f a[16];
#pragma unroll
            for (int j = 0; j < 16; j++) a[j] = (v2f)(0.0f);
            bacc4v(a, u);
            int tb = (node >> 4) * 64, nl = node & 15, kk = c4;
#pragma unroll
            for (int kg = 0; kg < 4; kg++)
                sA[(kk * 128 + tb + kg * 16 + nl) ^ (kk & 7)] = mk8(a + kg * 4, 1.0f);
        }
#else
        if (tid < 256) {
            int node = tid >> 3, c8 = tid & 7;  // cols c8*16..+15
            uint4 u = xb4[(size_t)(n0 + node) * 8 + c8];
            v2f a[8];
            a[0] = upk8<false>(u.x); a[1] = upk8<true>(u.x);
            a[2] = upk8<false>(u.y); a[3] = upk8<true>(u.y);
            a[4] = upk8<false>(u.z); a[5] = upk8<true>(u.z);
            a[6] = upk8<false>(u.w); a[7] = upk8<true>(u.w);
            int kk = c8 >> 1, kg0 = (c8 & 1) * 2;
            int tb = (node >> 4) * 64, nl = node & 15;
            sA[(kk * 128 + tb + kg0 * 16 + nl) ^ (kk & 7)]       = mk8(a, 1.0f);
            sA[(kk * 128 + tb + (kg0 + 1) * 16 + nl) ^ (kk & 7)] = mk8(a + 4, 1.0f);
        }
#endif
    }
    __syncthreads();   // fences binning writes (lcnt/ssrcL) before aggregation

    // ---- neighbor mean aggregation: 16 threads/node ----
    {
        const int nb = tid >> 4;           // node 0..31
        const int degt = lcnt[nb];
        const int degc = degt > NDCAP ? NDCAP : degt;
        const int* L = &ssrcL[nb * NDCAP];
        const int tb = (nb >> 4) * 64, nl = nb & 15;

        if constexpr (KS == HID) {
#if USE_FP4
            const int sub = tid & 15;
            const int l = sub & 3;          // uint4 index (4/row): cols l*32..+31
            const int h = sub >> 2;         // 4 chains
            v2f a[16];
#pragma unroll
            for (int j = 0; j < 16; j++) a[j] = (v2f)(0.0f);
            int i = h;
            for (; i + 4 < degc; i += 8) {
                int i0 = L[i], i1 = L[i + 4];
                uint4 v0 = xb4[(size_t)i0 * 4 + l];
                uint4 v1 = xb4[(size_t)i1 * 4 + l];
                bacc4v(a, v0);
                bacc4v(a, v1);
            }
            if (i < degc) bacc4v(a, xb4[(size_t)L[i] * 4 + l]);
#pragma unroll
            for (int j = 0; j < 16; j++) {
                a[j].x += __shfl_xor(a[j].x, 4);
                a[j].y += __shfl_xor(a[j].y, 4);
                a[j].x += __shfl_xor(a[j].x, 8);
                a[j].y += __shfl_xor(a[j].y, 8);
            }
            if (h == 0) {
                float iv = 1.0f / fmaxf((float)degt, 1.0f);
                int kk = 4 + l;
#pragma unroll
                for (int kg = 0; kg < 4; kg++)
                    sA[(kk * 128 + tb + kg * 16 + nl) ^ (kk & 7)] = mk8(a + kg * 4, iv);
            }
#else
            const int l = tid & 7;          // uint4 index (8/row): cols l*16..+15
            const int h = (tid >> 3) & 1;   // 2 chains
            v2f a[8];
#pragma unroll
            for (int j = 0; j < 8; j++) a[j] = (v2f)(0.0f);
            int i = h;
            for (; i + 2 < degc; i += 4) {
                int i0 = L[i], i1 = L[i + 2];
                uint4 v0 = xb4[(size_t)i0 * 8 + l];
                uint4 v1 = xb4[(size_t)i1 * 8 + l];
                bacc8v(a, v0);
                bacc8v(a, v1);
            }
            if (i < degc) bacc8v(a, xb4[(size_t)L[i] * 8 + l]);
#pragma unroll
            for (int j = 0; j < 8; j++) {
                a[j].x += __shfl_xor(a[j].x, 8);
                a[j].y += __shfl_xor(a[j].y, 8);
            }
            if (h == 0) {
                float iv = 1.0f / fmaxf((float)degt, 1.0f);
                int kk = 4 + (l >> 1), kg0 = (l & 1) * 2;
                sA[(kk * 128 + tb + kg0 * 16 + nl) ^ (kk & 7)]       = mk8(a, iv);
                sA[(kk * 128 + tb + (kg0 + 1) * 16 + nl) ^ (kk & 7)] = mk8(a + 4, iv);
            }
#endif
        } else {
            const int sub = tid & 15;
            const int l = sub & 3;          // uint4 index (4/row): cols l*16..+15
            const int h = sub >> 2;         // 4 chains
            v2f a[8];
#pragma unroll
            for (int j = 0; j < 8; j++) a[j] = (v2f)(0.0f);
            int i = h;
            for (; i + 4 < degc; i += 8) {
                int i0 = L[i], i1 = L[i + 4];
                uint4 v0 = xb4[(size_t)i0 * 4 + l];
                uint4 v1 = xb4[(size_t)i1 * 4 + l];
                bacc8v(a, v0);
                bacc8v(a, v1);
            }
            if (i < degc) bacc8v(a, xb4[(size_t)L[i] * 4 + l]);
#pragma unroll
            for (int j = 0; j < 8; j++) {
                a[j].x += __shfl_xor(a[j].x, 4);
                a[j].y += __shfl_xor(a[j].y, 4);
                a[j].x += __shfl_xor(a[j].x, 8);
                a[j].y += __shfl_xor(a[j].y, 8);
            }
            if (h == 0) {
                float iv = 1.0f / fmaxf((float)degt, 1.0f);
                int kk = 2 + (l >> 1), kg0 = (l & 1) * 2;
                sA[(kk * 128 + tb + kg0 * 16 + nl) ^ (kk & 7)]       = mk8(a, iv);
                sA[(kk * 128 + tb + (kg0 + 1) * 16 + nl) ^ (kk & 7)] = mk8(a + 4, iv);
            }
        }
    }
    __syncthreads();

    // ---- MFMA GEMM: 8 waves, wave q owns cols [16q,16q+16), 2 row-tiles ----
    const int lane = tid & 63;
    const int q = tid >> 6;
    const int r15 = lane & 15;
    const int kg = lane >> 4;
    f32x4 acc0 = {0.f, 0.f, 0.f, 0.f};   // rows 0..15
    f32x4 acc1 = {0.f, 0.f, 0.f, 0.f};   // rows 16..31

#pragma unroll
    for (int kk = 0; kk < KT; kk++) {
        short8v af0 = sA[(kk * 128 + lane) ^ (kk & 7)];
        short8v af1 = sA[(kk * 128 + 64 + lane) ^ (kk & 7)];
        short8v b0 = Wf[(kk * 8 + q) * 64 + lane];
        acc0 = __builtin_amdgcn_mfma_f32_16x16x32_bf16(af0, b0, acc0, 0, 0, 0);
        acc1 = __builtin_amdgcn_mfma_f32_16x16x32_bf16(af1, b0, acc1, 0, 0, 0);
    }
    // C/D layout (m89-verified): lane holds rows kg*4+i, col r15

    if constexpr (!REDUCE) {
        // relu -> fp32 otile transpose -> fp4/fp8 pack (coalesced stores)
#pragma unroll
        for (int i = 0; i < 4; i++) {
            otile[(kg * 4 + i) * 132 + 16 * q + r15]        = fmaxf(acc0[i], 0.f);
            otile[(16 + kg * 4 + i) * 132 + 16 * q + r15]   = fmaxf(acc1[i], 0.f);
        }
        __syncthreads();
        int node = tid >> 4, c = tid & 15;   // 8 cols per thread, 32 nodes
        float4 x0 = *(const float4*)&otile[node * 132 + c * 8];
        float4 x1 = *(const float4*)&otile[node * 132 + c * 8 + 4];
#if USE_FP4
        unsigned u = pk4<0>(0u, x0.x, x0.y);
        u = pk4<1>(u, x0.z, x0.w);
        u = pk4<2>(u, x1.x, x1.y);
        u = pk4<3>(u, x1.z, x1.w);
        unsigned* o4 = (unsigned*)(g ? outHb : outHa);
        o4[(size_t)(n0 + node) * 16 + c] = u;
#else
        unsigned w0 = pk8<false>(x0.x, x0.y, 0u); w0 = pk8<true>(x0.z, x0.w, w0);
        unsigned w1 = pk8<false>(x1.x, x1.y, 0u); w1 = pk8<true>(x1.z, x1.w, w1);
        uint2* o8 = (uint2*)(g ? outHb : outHa);
        o8[(size_t)(n0 + node) * 16 + c] = make_uint2(w0, w1);
#endif
    } else {
        // column sums of relu over the block's 32 nodes, then butterfly reduce
        float s0 = 0.f;
#pragma unroll
        for (int i = 0; i < 4; i++)
            s0 += fmaxf(acc0[i], 0.f) + fmaxf(acc1[i], 0.f);
        s0 += __shfl_xor(s0, 16); s0 += __shfl_xor(s0, 32);
        float* outR = g ? outRb : outRa;
        if (lane < 16) outR[(size_t)gid * 128 + 16 * q + lane] = s0;
    }
}

// ---------------------------------------------------------------------------
__global__ void reduce1_kernel(const float* __restrict__ p0, const float* __restrict__ p1,
                               float* __restrict__ p2) {
    const int bb = blockIdx.x;
    const int tid = threadIdx.x;
    const int g = tid >> 7;
    const int col = tid & 127;
    const float* p = g ? p1 : p0;
    const int per = NGRP / RBLK;   // 25
    float s = 0.0f;
    for (int r = 0; r < per; r++) s += p[(size_t)(bb * per + r) * 128 + col];
    p2[(size_t)bb * 256 + tid] = s;
}

__global__ void final_kernel(const float* __restrict__ p2,
                             const float* __restrict__ Wlin1,
                             const float* __restrict__ Wlin2,
                             float* __restrict__ out) {
    __shared__ float rep[2][HID];
    __shared__ float sg[32];
    const int tid = threadIdx.x;
    float s = 0.0f;
    for (int r = 0; r < RBLK; r++) s += p2[r * 256 + tid];
    rep[tid >> 7][tid & 127] = s * (1.0f / (float)NN);
    __syncthreads();
    if (tid < 32) {
        const int g = tid / 16;
        const int c = tid % 16;
        const float* W = g ? Wlin2 : Wlin1;
        float a = 0.0f;
        for (int k = 0; k < HID; k++) a += rep[g][k] * W[k * NCLS + c];
        sg[tid] = 1.0f / (1.0f + expf(-a));
    }
    __syncthreads();
    if (tid < 16) out[tid] = 0.5f * (sg[tid] + sg[16 + tid]);
}

// ---------------------------------------------------------------------------
extern "C" void kernel_launch(void* const* d_in, const int* in_sizes, int n_in,
                              void* d_out, int out_size, void* d_ws, size_t ws_size,
                              hipStream_t stream) {
    const float* feats = (const float*)d_in[0];
    const int* srcp[2] = {(const int*)d_in[1], (const int*)d_in[3]};
    const int* dstp[2] = {(const int*)d_in[2], (const int*)d_in[4]};
    const float* Ws1[2] = {(const float*)d_in[5], (const float*)d_in[10]};
    const float* Wn1[2] = {(const float*)d_in[6], (const float*)d_in[11]};
    const float* Ws2[2] = {(const float*)d_in[7], (const float*)d_in[12]};
    const float* Wn2[2] = {(const float*)d_in[8], (const float*)d_in[13]};
    const float* Wlin[2] = {(const float*)d_in[9], (const float*)d_in[14]};

    // workspace (~58 MB). coarse pairs alias the h1 table regions (regions
    // stay 12.8 MB each regardless of fp4 so the 7.2 MB pc alias is safe;
    // pc consumed by place_fine BEFORE the sage kernels write h1).
    const size_t PFN = (size_t)NCRS * 32 * CAPF;   // fine slots per graph
    char* w = (char*)d_ws;
    unsigned* fb8 = (unsigned*)w;   w += (size_t)NN * IND;          // 6.4 MB
    unsigned* h18a = (unsigned*)w;  w += (size_t)NN * HID;          // 12.8 MB region
    unsigned* h18b = (unsigned*)w;  w += (size_t)NN * HID;          // 12.8 MB region
    unsigned* pf0 = (unsigned*)w;   w += PFN * 4;                   // 8.2 MB
    unsigned* pf1 = (unsigned*)w;   w += PFN * 4;                   // 8.2 MB
    float* part0 = (float*)w;       w += (size_t)NGRP * 128 * 4;    // 1.6 MB
    float* part1 = (float*)w;       w += (size_t)NGRP * 128 * 4;    // 1.6 MB
    float* p2 = (float*)w;          w += (size_t)RBLK * 256 * 4;
    int* fcur = (int*)w;            w += (size_t)2 * NCRS * 32 * 4; // 25 KB
    int* gcurC = (int*)w;           w += 2 * NCRS * 4;              // contiguous w/ fcur
    w = (char*)(((uintptr_t)w + 15) & ~(uintptr_t)15);
    short* wpk = (short*)w;         w += 98304 * 2;                 // 192 KB bf16 B-frags
    unsigned* pc0 = h18a;           // alias (7.2 MB <= 12.8; dead before h1 writes)
    unsigned* pc1 = h18b;           // alias

    // zero all cursors in one memset (fcur and gcurC are contiguous)
    (void)hipMemsetAsync(fcur, 0, (size_t)(2 * NCRS * 32 + 2 * NCRS) * 4, stream);

    // merged prep (feats->fp8, weights->B-frags) + coarse multisplit
    prep_coarse<<<PCB + CVB + PKB, 512, 0, stream>>>(
        srcp[0], dstp[0], srcp[1], dstp[1], gcurC, pc0, pc1,
        (const float4*)feats, (uint4*)fb8,
        Ws1[0], Wn1[0], Ws1[1], Wn1[1],
        Ws2[0], Wn2[0], Ws2[1], Wn2[1], wpk);

    // fine multisplit (single-pass LDS staging)
    place_fine<<<2 * NCRS * FSPLIT, 512, 0, stream>>>(pc0, pc1, gcurC, pf0, pf1, fcur);

    // layer 1, both graphs in one dispatch (6250 blocks x 512)
    sage_fused<IND, false><<<2 * NGRP, 512, 0, stream>>>(
        feats, fb8, fb8, pf0, pf1, fcur,
        wpk, wpk + 16384,
        nullptr, nullptr, h18a, h18b);

    // layer 2, both graphs in one dispatch
    sage_fused<HID, true><<<2 * NGRP, 512, 0, stream>>>(
        nullptr, h18a, h18b, pf0, pf1, fcur,
        wpk + 32768, wpk + 65536,
        part0, part1, nullptr, nullptr);

    reduce1_kernel<<<RBLK, 256, 0, stream>>>(part0, part1, p2);
    final_kernel<<<1, 256, 0, stream>>>(p2, Wlin[0], Wlin[1], (float*)d_out);
}

// Round 14
// 266.765 us; speedup vs baseline: 1.1120x; 1.1120x over previous
//
#include <hip/hip_runtime.h>
#include <hip/hip_fp16.h>

#define NN 100000
#define NE 1600000
#define IND 64
#define HID 128
#define NCLS 16
#define NGRP 3125         // 32-node groups per graph (3125*32 = 100000 exactly)
#define RBLK 125          // reduce1 blocks (per = NGRP/RBLK = 25)
#define NCRS 98           // coarse buckets per graph (1024 nodes each)
#define CAPC 18432        // coarse capacity (mean 16384, sigma 128 -> +16 sigma)
#define CAPF 656          // fine capacity per 32-node group (mean 512, +6.4 sigma)
#define NDCAP 48          // per-node LDS list capacity (mean 16; P(>48)~1e-9)
#define EPB1 8192         // edges per block in place_coarse
#define NBG1 ((NE + EPB1 - 1) / EPB1)   // 196 blocks per graph
#define FSPLIT 4          // blocks per coarse bucket in place_fine
#define FSPAN ((CAPC + FSPLIT - 1) / FSPLIT)   // 4608 edges max per part
#define PCB (2 * NBG1)    // merged kernel: coarse blocks (392)
#define CVB 782           // merged kernel: conv blocks (400000/512)
#define PKB 24            // merged kernel: packW blocks (12288/512)

// fp4 h1 tables (halve layer-2 gather bytes) iff HW MX converters exist.
#if __has_builtin(__builtin_amdgcn_cvt_scalef32_pk_f32_fp4) && \
    __has_builtin(__builtin_amdgcn_cvt_scalef32_pk_fp4_f32)
#define USE_FP4 1
#else
#define USE_FP4 0
#endif

typedef float v2f __attribute__((ext_vector_type(2)));
typedef __attribute__((ext_vector_type(8))) short short8v;   // 8 bf16 (4 VGPRs)
typedef __attribute__((ext_vector_type(4))) float f32x4;     // MFMA acc

// ---------------------------------------------------------------------------
// fp8 e4m3 helpers (HW cvt on gfx950; template HI so builtin sees a constant)
__device__ __forceinline__ float fp8_sw_unpack(unsigned b) {
    unsigned s = (b >> 7) & 1u, em = b & 0x7fu;
    return __uint_as_float((s << 31) | (em << 20)) * 0x1p+120f;
}
__device__ __forceinline__ unsigned fp8_sw_pack(float f) {
    float c = fminf(fmaxf(f, -448.f), 448.f) * 0x1p-120f;
    unsigned b = __float_as_uint(c);
    unsigned s = b >> 31; b &= 0x7fffffffu;
    b = b + 0x7ffffu + ((b >> 20) & 1u);
    unsigned em = b >> 20;
    if (em > 0x7eu) em = 0x7eu;
    return (s << 7) | em;
}
template<bool HI>
__device__ __forceinline__ unsigned pk8(float a, float b, unsigned old) {
#if __has_builtin(__builtin_amdgcn_cvt_pk_fp8_f32)
    return (unsigned)__builtin_amdgcn_cvt_pk_fp8_f32(a, b, (int)old, HI);
#else
    unsigned v = fp8_sw_pack(a) | (fp8_sw_pack(b) << 8);
    return HI ? ((old & 0x0000ffffu) | (v << 16)) : ((old & 0xffff0000u) | v);
#endif
}
template<bool HI>
__device__ __forceinline__ v2f upk8(unsigned u) {
#if __has_builtin(__builtin_amdgcn_cvt_pk_f32_fp8)
    return __builtin_amdgcn_cvt_pk_f32_fp8((int)u, HI);
#else
    unsigned x = HI ? (u >> 16) : u;
    v2f r; r.x = fp8_sw_unpack(x & 0xffu); r.y = fp8_sw_unpack((x >> 8) & 0xffu);
    return r;
#endif
}

// float -> bf16 bits (RNE) -- scalar fallback path
__device__ __forceinline__ short f2bf(float f) {
    unsigned u = __float_as_uint(f);
    return (short)((u + 0x7fffu + ((u >> 16) & 1u)) >> 16);
}

// HW packed f32x2 -> bf16x2 (RNE; gfx950 v_cvt_pk_bf16_f32, T12-verified)
__device__ __forceinline__ unsigned cvt2bf(float a, float b) {
    unsigned r;
    asm("v_cvt_pk_bf16_f32 %0, %1, %2" : "=v"(r) : "v"(a), "v"(b));
    return r;
}

// packed-fp32 accumulate: 8 cvt_pk + 8 v_pk_add_f32 per uint4 (16 fp8 vals)
__device__ __forceinline__ void bacc8v(v2f* a, uint4 v) {
    a[0] += upk8<false>(v.x); a[1] += upk8<true>(v.x);
    a[2] += upk8<false>(v.y); a[3] += upk8<true>(v.y);
    a[4] += upk8<false>(v.z); a[5] += upk8<true>(v.z);
    a[6] += upk8<false>(v.w); a[7] += upk8<true>(v.w);
}

#if USE_FP4
// fp4 accumulate from uint2 (16 fp4 vals): 8 cvt + 8 pk_add -- SAME register
// footprint as bacc8v (a[8] v2f), fixing R13's VGPR/occupancy collapse.
__device__ __forceinline__ void bacc4v2(v2f* a, uint2 v) {
    a[0] += __builtin_amdgcn_cvt_scalef32_pk_f32_fp4(v.x, 1.0f, 0);
    a[1] += __builtin_amdgcn_cvt_scalef32_pk_f32_fp4(v.x, 1.0f, 1);
    a[2] += __builtin_amdgcn_cvt_scalef32_pk_f32_fp4(v.x, 1.0f, 2);
    a[3] += __builtin_amdgcn_cvt_scalef32_pk_f32_fp4(v.x, 1.0f, 3);
    a[4] += __builtin_amdgcn_cvt_scalef32_pk_f32_fp4(v.y, 1.0f, 0);
    a[5] += __builtin_amdgcn_cvt_scalef32_pk_f32_fp4(v.y, 1.0f, 1);
    a[6] += __builtin_amdgcn_cvt_scalef32_pk_f32_fp4(v.y, 1.0f, 2);
    a[7] += __builtin_amdgcn_cvt_scalef32_pk_f32_fp4(v.y, 1.0f, 3);
}
// pack 2 relu-f32 into byte SEL of a fp4 word (clamp to e2m1 max 6)
template<int SEL>
__device__ __forceinline__ unsigned pk4(unsigned old, float a, float b) {
    return __builtin_amdgcn_cvt_scalef32_pk_fp4_f32(old, fminf(a, 6.0f),
                                                    fminf(b, 6.0f), 1.0f, SEL);
}
#endif

// 4 v2f (8 floats) * iv -> one bf16 granule (4 pk_mul + 4 cvt_pk = 8 VALU)
__device__ __forceinline__ short8v mk8(const v2f* a, float iv) {
    union { uint4 u; short8v s; } o;
    v2f t0 = a[0] * iv, t1 = a[1] * iv, t2 = a[2] * iv, t3 = a[3] * iv;
    o.u.x = cvt2bf(t0.x, t0.y);
    o.u.y = cvt2bf(t1.x, t1.y);
    o.u.z = cvt2bf(t2.x, t2.y);
    o.u.w = cvt2bf(t3.x, t3.y);
    return o.s;
}

// ---------------------------------------------------------------------------
// Merged prep + place_coarse (independent work; cursor zeroing precedes via
// memset). Blocks [0,392): coarse multisplit; [392,1174): feats->fp8;
// [1174,1198): weights->B-frags.
__global__ __launch_bounds__(512) void prep_coarse(
    const int* __restrict__ s0, const int* __restrict__ d0,
    const int* __restrict__ s1, const int* __restrict__ d1,
    int* __restrict__ gcurC,
    unsigned* __restrict__ pc0, unsigned* __restrict__ pc1,
    const float4* __restrict__ x, uint4* __restrict__ o8,
    const float* __restrict__ Ws1a, const float* __restrict__ Wn1a,
    const float* __restrict__ Ws1b, const float* __restrict__ Wn1b,
    const float* __restrict__ Ws2a, const float* __restrict__ Wn2a,
    const float* __restrict__ Ws2b, const float* __restrict__ Wn2b,
    short* __restrict__ wout) {
    __shared__ unsigned ebuf[EPB1];      // 32 KB, bucket-ordered edges
    __shared__ int h[128], off[128];     // hist / inclusive scan (98 used)
    __shared__ int hb[NCRS];             // reserved global base per bucket
    const int bi = blockIdx.x;
    const int tid = threadIdx.x;

    if (bi >= PCB) {
        if (bi < PCB + CVB) {
            // feats fp32 -> fp8 (16 elems / thread)
            int i = (bi - PCB) * 512 + tid;
            if (i >= NN * IND / 16) return;
            float4 v0 = x[4 * i + 0], v1 = x[4 * i + 1];
            float4 v2 = x[4 * i + 2], v3 = x[4 * i + 3];
            uint4 u;
            u.x = pk8<true>(v0.z, v0.w, pk8<false>(v0.x, v0.y, 0u));
            u.y = pk8<true>(v1.z, v1.w, pk8<false>(v1.x, v1.y, 0u));
            u.z = pk8<true>(v2.z, v2.w, pk8<false>(v2.x, v2.y, 0u));
            u.w = pk8<true>(v3.z, v3.w, pk8<false>(v3.x, v3.y, 0u));
            o8[i] = u;
        } else {
            // pack [Ws;Wn] stacks into bf16 MFMA B-fragments
            int t = (bi - PCB - CVB) * 512 + tid;
            if (t >= 12288) return;
            const float *Ws, *Wn; short* o; int KS;
            if (t < 2048)      { Ws = Ws1a; Wn = Wn1a; o = wout;         KS = 64;  }
            else if (t < 4096) { Ws = Ws1b; Wn = Wn1b; o = wout + 16384; KS = 64;  t -= 2048; }
            else if (t < 8192) { Ws = Ws2a; Wn = Wn2a; o = wout + 32768; KS = 128; t -= 4096; }
            else               { Ws = Ws2b; Wn = Wn2b; o = wout + 65536; KS = 128; t -= 8192; }
            int l = t & 63, f = t >> 6, nn = f & 7, kk = f >> 3;
            int col = nn * 16 + (l & 15);
            int k0 = kk * 32 + ((l >> 4) * 8);
            unsigned short v[8];
#pragma unroll
            for (int j = 0; j < 8; j++) {
                int k = k0 + j;
                float xx = (k < KS) ? Ws[k * 128 + col] : Wn[(k - KS) * 128 + col];
                v[j] = (unsigned short)f2bf(xx);
            }
            uint4 u;
            u.x = (unsigned)v[0] | ((unsigned)v[1] << 16);
            u.y = (unsigned)v[2] | ((unsigned)v[3] << 16);
            u.z = (unsigned)v[4] | ((unsigned)v[5] << 16);
            u.w = (unsigned)v[6] | ((unsigned)v[7] << 16);
            ((uint4*)o)[t] = u;
        }
        return;
    }

    // ---- coarse multisplit: entry = src | (dst&1023)<<17 ----
    const int g = bi >= NBG1;
    const int* src = g ? s1 : s0;
    const int* dst = g ? d1 : d0;
    unsigned* pc = g ? pc1 : pc0;
    const int base = (g ? bi - NBG1 : bi) * EPB1;
    int nle = NE - base; if (nle > EPB1) nle = EPB1;

    if (tid < 128) h[tid] = 0;
    __syncthreads();
    for (int j = tid; j < nle; j += 512) atomicAdd(&h[dst[base + j] >> 10], 1);
    __syncthreads();
    if (tid < 128) off[tid] = h[tid];
    __syncthreads();
    for (int o = 1; o < 128; o <<= 1) {
        int v = (tid < 128 && tid >= o) ? off[tid - o] : 0;
        __syncthreads();
        if (tid < 128) off[tid] += v;
        __syncthreads();
    }
    if (tid < NCRS) hb[tid] = h[tid] ? atomicAdd(&gcurC[g * NCRS + tid], h[tid]) : 0;
    __syncthreads();
    if (tid < 128) h[tid] = off[tid] - h[tid];   // h becomes scatter cursor (excl)
    __syncthreads();
    for (int j = tid; j < nle; j += 512) {
        int d = dst[base + j];
        int b = d >> 10;
        int pos = atomicAdd(&h[b], 1);
        ebuf[pos] = (unsigned)src[base + j] | ((unsigned)(d & 1023) << 17);
    }
    __syncthreads();
    const int wv = tid >> 6, lane = tid & 63;
    for (int b = wv; b < NCRS; b += 8) {
        int beg = b ? off[b - 1] : 0;
        int run = off[b] - beg;
        int gb = hb[b];
        if (gb + run > CAPC) run = CAPC - gb;
        for (int i = lane; i < run; i += 64)
            pc[(size_t)b * CAPC + gb + i] = ebuf[beg + i];
    }
}

// ---------------------------------------------------------------------------
// Level 2: FSPLIT blocks per coarse bucket; SINGLE-PASS LDS multisplit into
// 32 fine bins (32-node groups), global atomic cursor reservation, coalesced
// writeback. fine entry = src | (dst&31)<<17
__global__ __launch_bounds__(512) void place_fine(
    const unsigned* __restrict__ pc0, const unsigned* __restrict__ pc1,
    const int* __restrict__ gcurC,
    unsigned* __restrict__ pf0, unsigned* __restrict__ pf1,
    int* __restrict__ fcur) {      // [2][NCRS*32]
    __shared__ unsigned ibuf[FSPAN];     // 18.4 KB, raw slice
    __shared__ unsigned obuf[FSPAN];     // 18.4 KB, bin-ordered slice
    __shared__ int h2[32], off2[32], cur2[32], gb2[32];
    const int bi = blockIdx.x;
    const int g = bi >= NCRS * FSPLIT;
    const int idx = g ? bi - NCRS * FSPLIT : bi;
    const int c = idx >> 2, part = idx & (FSPLIT - 1);
    const unsigned* pc = g ? pc1 : pc0;
    unsigned* pf = g ? pf1 : pf0;
    int* fc = fcur + (size_t)g * NCRS * 32;
    int ecnt = gcurC[g * NCRS + c];
    if (ecnt > CAPC) ecnt = CAPC;
    int span = (ecnt + FSPLIT - 1) / FSPLIT;
    int st = part * span;
    int en = st + span; if (en > ecnt) en = ecnt;
    int n = en - st; if (n < 0) n = 0;
    const size_t cb = (size_t)c * CAPC + st;
    const int tid = threadIdx.x;
    const int wv = tid >> 6, lane = tid & 63;

    if (tid < 32) h2[tid] = 0;
    __syncthreads();
    for (int e = tid; e < n; e += 512) {
        unsigned u = pc[cb + e];
        ibuf[e] = u;
        atomicAdd(&h2[(u >> 22) & 31], 1);
    }
    __syncthreads();
    if (tid < 32) {
        gb2[tid] = h2[tid] ? atomicAdd(&fc[c * 32 + tid], h2[tid]) : 0;
        off2[tid] = h2[tid];
    }
    __syncthreads();
    for (int o = 1; o < 32; o <<= 1) {
        int v = (tid < 32 && tid >= o) ? off2[tid - o] : 0;
        __syncthreads();
        if (tid < 32) off2[tid] += v;
        __syncthreads();
    }
    if (tid < 32) cur2[tid] = off2[tid] - h2[tid];
    __syncthreads();
    for (int e = tid; e < n; e += 512) {
        unsigned u = ibuf[e];
        int sub = (u >> 22) & 31;
        int pos = atomicAdd(&cur2[sub], 1);
        obuf[pos] = (u & 0x1FFFFu) | (((u >> 17) & 31u) << 17);
    }
    __syncthreads();
    for (int sub = wv; sub < 32; sub += 8) {
        int beg = sub ? off2[sub - 1] : 0;
        int run = off2[sub] - beg;
        int gb = gb2[sub];
        if (gb >= CAPF) run = 0;
        else if (gb + run > CAPF) run = CAPF - gb;
        for (int i = lane; i < run; i += 64)
            pf[(size_t)(c * 32 + sub) * CAPF + gb + i] = obuf[beg + i];
    }
}

// ---------------------------------------------------------------------------
// Merged-graph fused SAGE layer: 512 threads, 32 nodes/block (16 thr/node),
// grid = 2*NGRP. The __syncthreads() after self-staging fences the binning
// writes (lcnt/ssrcL) that aggregation reads (R7 lesson).
// h1 tables are fp4 (64B rows) when USE_FP4; gather uses uint2 (8B) loads so
// the accumulator stays a[8] v2f (R13's a[16] blew VGPR 32->56, occ 75->41).
template<int KS, bool REDUCE>
__global__ __launch_bounds__(512) void sage_fused(
    const float* __restrict__ xin,
    const unsigned* __restrict__ x8a, const unsigned* __restrict__ x8b,
    const unsigned* __restrict__ pf0, const unsigned* __restrict__ pf1,
    const int* __restrict__ fcur,
    const short* __restrict__ Wfa, const short* __restrict__ Wfb,
    float* __restrict__ outRa, float* __restrict__ outRb,
    unsigned* __restrict__ outHa, unsigned* __restrict__ outHb) {
    constexpr int KT = (2 * KS) / 32;          // K-steps of 32
    __shared__ short8v sA[KT * 128];           // 2*KT KB (8 KB / 16 KB)
    __shared__ float otile[REDUCE ? 1 : 32 * 132];  // fp32 C transpose (layer1)
    __shared__ int lcnt[32];
    __shared__ int ssrcL[32 * NDCAP];          // per-node neighbor lists (6 KB)

    const int tid = threadIdx.x;
    const int g = blockIdx.x >= NGRP;
    const int gid = g ? blockIdx.x - NGRP : blockIdx.x;
    const int n0 = gid * 32;
    const unsigned* x8 = g ? x8b : x8a;
    const unsigned* pf = g ? pf1 : pf0;
    const int* fc = fcur + (size_t)g * NCRS * 32;
    const short8v* Wf = (const short8v*)(g ? Wfb : Wfa);
    const uint4* xb4 = (const uint4*)x8;

    if (tid < 32) lcnt[tid] = 0;
    __syncthreads();

    // ---- in-block binning: fine region -> per-node LDS lists ----
    {
        int ecnt = fc[gid];
        if (ecnt > CAPF) ecnt = CAPF;
        for (int e = tid; e < ecnt; e += 512) {
            unsigned u = pf[(size_t)gid * CAPF + e];
            int loc = (u >> 17) & 31;
            int pos = atomicAdd(&lcnt[loc], 1);
            if (pos < NDCAP) ssrcL[loc * NDCAP + pos] = (int)(u & 0x1FFFFu);
        }
    }

    // ---- self staging (256 threads, cols c8*16..+15 each) ----
    if (tid < 256) {
        int node = tid >> 3, c8 = tid & 7;
        int tb = (node >> 4) * 64, nl = node & 15;
        int kk = c8 >> 1, kg0 = (c8 & 1) * 2;
        if constexpr (KS == IND) {
            int r = tid & 7;   // cols r*8..r*8+7
            float4 v0 = ((const float4*)xin)[(size_t)(n0 + node) * 16 + r * 2];
            float4 v1 = ((const float4*)xin)[(size_t)(n0 + node) * 16 + r * 2 + 1];
            union { uint4 u; short8v s; } o;
            o.u.x = cvt2bf(v0.x, v0.y);
            o.u.y = cvt2bf(v0.z, v0.w);
            o.u.z = cvt2bf(v1.x, v1.y);
            o.u.w = cvt2bf(v1.z, v1.w);
            int kk1 = r >> 2, kg = r & 3;
            sA[(kk1 * 128 + tb + kg * 16 + nl) ^ (kk1 & 7)] = o.s;
        } else {
#if USE_FP4
            uint2 u = ((const uint2*)x8)[(size_t)(n0 + node) * 8 + c8];
            v2f a[8];
#pragma unroll
            for (int j = 0; j < 8; j++) a[j] = (v2f)(0.0f);
            bacc4v2(a, u);
#else
            uint4 u = xb4[(size_t)(n0 + node) * 8 + c8];
            v2f a[8];
            a[0] = upk8<false>(u.x); a[1] = upk8<true>(u.x);
            a[2] = upk8<false>(u.y); a[3] = upk8<true>(u.y);
            a[4] = upk8<false>(u.z); a[5] = upk8<true>(u.z);
            a[6] = upk8<false>(u.w); a[7] = upk8<true>(u.w);
#endif
            sA[(kk * 128 + tb + kg0 * 16 + nl) ^ (kk & 7)]       = mk8(a, 1.0f);
            sA[(kk * 128 + tb + (kg0 + 1) * 16 + nl) ^ (kk & 7)] = mk8(a + 4, 1.0f);
        }
    }
    __syncthreads();   // fences binning writes (lcnt/ssrcL) before aggregation

    // ---- neighbor mean aggregation: 16 threads/node ----
    {
        const int nb = tid >> 4;           // node 0..31
        const int degt = lcnt[nb];
        const int degc = degt > NDCAP ? NDCAP : degt;
        const int* L = &ssrcL[nb * NDCAP];
        const int tb = (nb >> 4) * 64, nl = nb & 15;

        if constexpr (KS == HID) {
            const int l = tid & 7;          // cols l*16..+15
            const int h = (tid >> 3) & 1;   // 2 chains
            v2f a[8];
#pragma unroll
            for (int j = 0; j < 8; j++) a[j] = (v2f)(0.0f);
            int i = h;
#if USE_FP4
            const uint2* xb2 = (const uint2*)x8;
            for (; i + 2 < degc; i += 4) {
                int i0 = L[i], i1 = L[i + 2];
                uint2 v0 = xb2[(size_t)i0 * 8 + l];
                uint2 v1 = xb2[(size_t)i1 * 8 + l];
                bacc4v2(a, v0);
                bacc4v2(a, v1);
            }
            if (i < degc) bacc4v2(a, xb2[(size_t)L[i] * 8 + l]);
#else
            for (; i + 2 < degc; i += 4) {
                int i0 = L[i], i1 = L[i + 2];
                uint4 v0 = xb4[(size_t)i0 * 8 + l];
                uint4 v1 = xb4[(size_t)i1 * 8 + l];
                bacc8v(a, v0);
                bacc8v(a, v1);
            }
            if (i < degc) bacc8v(a, xb4[(size_t)L[i] * 8 + l]);
#endif
#pragma unroll
            for (int j = 0; j < 8; j++) {
                a[j].x += __shfl_xor(a[j].x, 8);
                a[j].y += __shfl_xor(a[j].y, 8);
            }
            if (h == 0) {
                float iv = 1.0f / fmaxf((float)degt, 1.0f);
                int kk = 4 + (l >> 1), kg0 = (l & 1) * 2;
                sA[(kk * 128 + tb + kg0 * 16 + nl) ^ (kk & 7)]       = mk8(a, iv);
                sA[(kk * 128 + tb + (kg0 + 1) * 16 + nl) ^ (kk & 7)] = mk8(a + 4, iv);
            }
        } else {
            const int sub = tid & 15;
            const int l = sub & 3;          // uint4 index (4/row): cols l*16..+15
            const int h = sub >> 2;         // 4 chains
            v2f a[8];
#pragma unroll
            for (int j = 0; j < 8; j++) a[j] = (v2f)(0.0f);
            int i = h;
            for (; i + 4 < degc; i += 8) {
                int i0 = L[i], i1 = L[i + 4];
                uint4 v0 = xb4[(size_t)i0 * 4 + l];
                uint4 v1 = xb4[(size_t)i1 * 4 + l];
                bacc8v(a, v0);
                bacc8v(a, v1);
            }
            if (i < degc) bacc8v(a, xb4[(size_t)L[i] * 4 + l]);
#pragma unroll
            for (int j = 0; j < 8; j++) {
                a[j].x += __shfl_xor(a[j].x, 4);
                a[j].y += __shfl_xor(a[j].y, 4);
                a[j].x += __shfl_xor(a[j].x, 8);
                a[j].y += __shfl_xor(a[j].y, 8);
            }
            if (h == 0) {
                float iv = 1.0f / fmaxf((float)degt, 1.0f);
                int kk = 2 + (l >> 1), kg0 = (l & 1) * 2;
                sA[(kk * 128 + tb + kg0 * 16 + nl) ^ (kk & 7)]       = mk8(a, iv);
                sA[(kk * 128 + tb + (kg0 + 1) * 16 + nl) ^ (kk & 7)] = mk8(a + 4, iv);
            }
        }
    }
    __syncthreads();

    // ---- MFMA GEMM: 8 waves, wave q owns cols [16q,16q+16), 2 row-tiles ----
    const int lane = tid & 63;
    const int q = tid >> 6;
    const int r15 = lane & 15;
    const int kg = lane >> 4;
    f32x4 acc0 = {0.f, 0.f, 0.f, 0.f};   // rows 0..15
    f32x4 acc1 = {0.f, 0.f, 0.f, 0.f};   // rows 16..31

#pragma unroll
    for (int kk = 0; kk < KT; kk++) {
        short8v af0 = sA[(kk * 128 + lane) ^ (kk & 7)];
        short8v af1 = sA[(kk * 128 + 64 + lane) ^ (kk & 7)];
        short8v b0 = Wf[(kk * 8 + q) * 64 + lane];
        acc0 = __builtin_amdgcn_mfma_f32_16x16x32_bf16(af0, b0, acc0, 0, 0, 0);
        acc1 = __builtin_amdgcn_mfma_f32_16x16x32_bf16(af1, b0, acc1, 0, 0, 0);
    }
    // C/D layout (m89-verified): lane holds rows kg*4+i, col r15

    if constexpr (!REDUCE) {
        // relu -> fp32 otile transpose -> fp4/fp8 pack (coalesced stores)
#pragma unroll
        for (int i = 0; i < 4; i++) {
            otile[(kg * 4 + i) * 132 + 16 * q + r15]        = fmaxf(acc0[i], 0.f);
            otile[(16 + kg * 4 + i) * 132 + 16 * q + r15]   = fmaxf(acc1[i], 0.f);
        }
        __syncthreads();
        int node = tid >> 4, c = tid & 15;   // 8 cols per thread, 32 nodes
        float4 x0 = *(const float4*)&otile[node * 132 + c * 8];
        float4 x1 = *(const float4*)&otile[node * 132 + c * 8 + 4];
#if USE_FP4
        unsigned u = pk4<0>(0u, x0.x, x0.y);
        u = pk4<1>(u, x0.z, x0.w);
        u = pk4<2>(u, x1.x, x1.y);
        u = pk4<3>(u, x1.z, x1.w);
        unsigned* o4 = (unsigned*)(g ? outHb : outHa);
        o4[(size_t)(n0 + node) * 16 + c] = u;
#else
        unsigned w0 = pk8<false>(x0.x, x0.y, 0u); w0 = pk8<true>(x0.z, x0.w, w0);
        unsigned w1 = pk8<false>(x1.x, x1.y, 0u); w1 = pk8<true>(x1.z, x1.w, w1);
        uint2* o8 = (uint2*)(g ? outHb : outHa);
        o8[(size_t)(n0 + node) * 16 + c] = make_uint2(w0, w1);
#endif
    } else {
        // column sums of relu over the block's 32 nodes, then butterfly reduce
        float s0 = 0.f;
#pragma unroll
        for (int i = 0; i < 4; i++)
            s0 += fmaxf(acc0[i], 0.f) + fmaxf(acc1[i], 0.f);
        s0 += __shfl_xor(s0, 16); s0 += __shfl_xor(s0, 32);
        float* outR = g ? outRb : outRa;
        if (lane < 16) outR[(size_t)gid * 128 + 16 * q + lane] = s0;
    }
}

// ---------------------------------------------------------------------------
__global__ void reduce1_kernel(const float* __restrict__ p0, const float* __restrict__ p1,
                               float* __restrict__ p2) {
    const int bb = blockIdx.x;
    const int tid = threadIdx.x;
    const int g = tid >> 7;
    const int col = tid & 127;
    const float* p = g ? p1 : p0;
    const int per = NGRP / RBLK;   // 25
    float s = 0.0f;
    for (int r = 0; r < per; r++) s += p[(size_t)(bb * per + r) * 128 + col];
    p2[(size_t)bb * 256 + tid] = s;
}

__global__ void final_kernel(const float* __restrict__ p2,
                             const float* __restrict__ Wlin1,
                             const float* __restrict__ Wlin2,
                             float* __restrict__ out) {
    __shared__ float rep[2][HID];
    __shared__ float sg[32];
    const int tid = threadIdx.x;
    float s = 0.0f;
    for (int r = 0; r < RBLK; r++) s += p2[r * 256 + tid];
    rep[tid >> 7][tid & 127] = s * (1.0f / (float)NN);
    __syncthreads();
    if (tid < 32) {
        const int g = tid / 16;
        const int c = tid % 16;
        const float* W = g ? Wlin2 : Wlin1;
        float a = 0.0f;
        for (int k = 0; k < HID; k++) a += rep[g][k] * W[k * NCLS + c];
        sg[tid] = 1.0f / (1.0f + expf(-a));
    }
    __syncthreads();
    if (tid < 16) out[tid] = 0.5f * (sg[tid] + sg[16 + tid]);
}

// ---------------------------------------------------------------------------
extern "C" void kernel_launch(void* const* d_in, const int* in_sizes, int n_in,
                              void* d_out, int out_size, void* d_ws, size_t ws_size,
                              hipStream_t stream) {
    const float* feats = (const float*)d_in[0];
    const int* srcp[2] = {(const int*)d_in[1], (const int*)d_in[3]};
    const int* dstp[2] = {(const int*)d_in[2], (const int*)d_in[4]};
    const float* Ws1[2] = {(const float*)d_in[5], (const float*)d_in[10]};
    const float* Wn1[2] = {(const float*)d_in[6], (const float*)d_in[11]};
    const float* Ws2[2] = {(const float*)d_in[7], (const float*)d_in[12]};
    const float* Wn2[2] = {(const float*)d_in[8], (const float*)d_in[13]};
    const float* Wlin[2] = {(const float*)d_in[9], (const float*)d_in[14]};

    // workspace (~58 MB). coarse pairs alias the h1 table regions (regions
    // stay 12.8 MB each regardless of fp4 so the 7.2 MB pc alias is safe;
    // pc consumed by place_fine BEFORE the sage kernels write h1).
    const size_t PFN = (size_t)NCRS * 32 * CAPF;   // fine slots per graph
    char* w = (char*)d_ws;
    unsigned* fb8 = (unsigned*)w;   w += (size_t)NN * IND;          // 6.4 MB
    unsigned* h18a = (unsigned*)w;  w += (size_t)NN * HID;          // 12.8 MB region
    unsigned* h18b = (unsigned*)w;  w += (size_t)NN * HID;          // 12.8 MB region
    unsigned* pf0 = (unsigned*)w;   w += PFN * 4;                   // 8.2 MB
    unsigned* pf1 = (unsigned*)w;   w += PFN * 4;                   // 8.2 MB
    float* part0 = (float*)w;       w += (size_t)NGRP * 128 * 4;    // 1.6 MB
    float* part1 = (float*)w;       w += (size_t)NGRP * 128 * 4;    // 1.6 MB
    float* p2 = (float*)w;          w += (size_t)RBLK * 256 * 4;
    int* fcur = (int*)w;            w += (size_t)2 * NCRS * 32 * 4; // 25 KB
    int* gcurC = (int*)w;           w += 2 * NCRS * 4;              // contiguous w/ fcur
    w = (char*)(((uintptr_t)w + 15) & ~(uintptr_t)15);
    short* wpk = (short*)w;         w += 98304 * 2;                 // 192 KB bf16 B-frags
    unsigned* pc0 = h18a;           // alias (7.2 MB <= 12.8; dead before h1 writes)
    unsigned* pc1 = h18b;           // alias

    // zero all cursors in one memset (fcur and gcurC are contiguous)
    (void)hipMemsetAsync(fcur, 0, (size_t)(2 * NCRS * 32 + 2 * NCRS) * 4, stream);

    // merged prep (feats->fp8, weights->B-frags) + coarse multisplit
    prep_coarse<<<PCB + CVB + PKB, 512, 0, stream>>>(
        srcp[0], dstp[0], srcp[1], dstp[1], gcurC, pc0, pc1,
        (const float4*)feats, (uint4*)fb8,
        Ws1[0], Wn1[0], Ws1[1], Wn1[1],
        Ws2[0], Wn2[0], Ws2[1], Wn2[1], wpk);

    // fine multisplit (single-pass LDS staging)
    place_fine<<<2 * NCRS * FSPLIT, 512, 0, stream>>>(pc0, pc1, gcurC, pf0, pf1, fcur);

    // layer 1, both graphs in one dispatch (6250 blocks x 512)
    sage_fused<IND, false><<<2 * NGRP, 512, 0, stream>>>(
        feats, fb8, fb8, pf0, pf1, fcur,
        wpk, wpk + 16384,
        nullptr, nullptr, h18a, h18b);

    // layer 2, both graphs in one dispatch
    sage_fused<HID, true><<<2 * NGRP, 512, 0, stream>>>(
        nullptr, h18a, h18b, pf0, pf1, fcur,
        wpk + 32768, wpk + 65536,
        part0, part1, nullptr, nullptr);

    reduce1_kernel<<<RBLK, 256, 0, stream>>>(part0, part1, p2);
    final_kernel<<<1, 256, 0, stream>>>(p2, Wlin[0], Wlin[1], (float*)d_out);
}